// Round 9
// baseline (239.155 us; speedup 1.0000x reference)
//
#include <hip/hip_runtime.h>

typedef __attribute__((ext_vector_type(8))) __bf16 bf16x8;
typedef __attribute__((ext_vector_type(4))) __bf16 bf16x4;
typedef __attribute__((ext_vector_type(4))) float f32x4;

#define DEVFN static __device__ __forceinline__

#if __has_builtin(__builtin_amdgcn_exp2f)
#define EXP2(x) __builtin_amdgcn_exp2f(x)
#else
#define EXP2(x) exp2f(x)
#endif

DEVFN f32x4 mfma16(bf16x8 a, bf16x8 b, f32x4 c) {
  return __builtin_amdgcn_mfma_f32_16x16x32_bf16(a, b, c, 0, 0, 0);
}

DEVFN void gload16(const void* g, void* l) {
  __builtin_amdgcn_global_load_lds((const __attribute__((address_space(1))) void*)g,
                                   (__attribute__((address_space(3))) void*)l, 16, 0, 0);
}

// ---------------------------------------------------------------------------
// Transpose+convert weights: W fp32 [1024 k][1024 n] -> Wt bf16 [n][k] swizzled
// ---------------------------------------------------------------------------
__global__ __launch_bounds__(256) void transW4(const float* __restrict__ w0,
                                               const float* __restrict__ w1,
                                               const float* __restrict__ w2,
                                               const float* __restrict__ w3,
                                               unsigned short* __restrict__ obase) {
  __shared__ float t[64][65];
  const float* W = blockIdx.z == 0 ? w0 : blockIdx.z == 1 ? w1 : blockIdx.z == 2 ? w2 : w3;
  unsigned short* Wt = obase + ((size_t)blockIdx.z << 20);
  int k0 = blockIdx.x * 64, n0 = blockIdx.y * 64;
  int tid = threadIdx.x;
#pragma unroll
  for (int it = 0; it < 4; ++it) {
    int r = it * 16 + (tid >> 4);
    int c = (tid & 15) * 4;
    float4 v = *(const float4*)(W + (size_t)(k0 + r) * 1024 + n0 + c);
    t[r][c] = v.x; t[r][c + 1] = v.y; t[r][c + 2] = v.z; t[r][c + 3] = v.w;
  }
  __syncthreads();
#pragma unroll
  for (int it = 0; it < 2; ++it) {
    int nl = it * 32 + (tid >> 3);
    int kc = tid & 7;
    bf16x8 o;
#pragma unroll
    for (int j = 0; j < 8; ++j) o[j] = (__bf16)t[kc * 8 + j][nl];
    int n = n0 + nl;
    char* dst = (char*)Wt + (size_t)n * 2048 + (k0 << 1) + ((kc ^ (n & 7)) << 4);
    *(bf16x8*)dst = o;
  }
}

// ---------------------------------------------------------------------------
// GEMM C = A[4096x1024] * Bt[1024x1024]^T (+bias)*scale  (unchanged from R8)
// ---------------------------------------------------------------------------
struct GArg {
  const void* A;
  const unsigned short* Bt;
  const float* bias;
  void* out;
  float scale;
};

template <int BM, int BN, int WR, int WC, int AF32, int EPI, int OCC>
__global__ __launch_bounds__(256, OCC) void gemm_t(GArg g0, GArg g1, GArg g2) {
  GArg g = blockIdx.z == 0 ? g0 : blockIdx.z == 1 ? g1 : g2;
  constexpr int MT = BM / WR / 16, NT = BN / WC / 16;
  constexpr int AB = AF32 ? 4 : 2;
  __shared__ char lA[BM * 64 * AB];
  __shared__ char lB[BN * 64 * 2];
  int tid = threadIdx.x, wave = tid >> 6, lane = tid & 63;
  int hi = lane >> 4, lo = lane & 15;
  int m0 = blockIdx.x * BM, n0 = blockIdx.y * BN;
  int wr = wave / WC, wc = wave % WC;
  f32x4 acc[MT][NT];
#pragma unroll
  for (int mt = 0; mt < MT; ++mt)
#pragma unroll
    for (int nt = 0; nt < NT; ++nt) acc[mt][nt] = (f32x4){0.f, 0.f, 0.f, 0.f};

  for (int k0 = 0; k0 < 1024; k0 += 64) {
    if (AF32) {
#pragma unroll
      for (int i = 0; i < BM / 16; ++i) {
        int off = i * 4096 + tid * 16;
        int row = off >> 8, b = off & 255;
        gload16((const char*)g.A + (size_t)(m0 + row) * 4096 + (k0 << 2)
                    + (b ^ ((row & 7) << 4)),
                lA + i * 4096 + wave * 1024);
      }
    } else {
#pragma unroll
      for (int i = 0; i < BM / 32; ++i) {
        int off = i * 4096 + tid * 16;
        int row = off >> 7, b = off & 127;
        gload16((const char*)g.A + (size_t)(m0 + row) * 2048 + (k0 << 1) + b,
                lA + i * 4096 + wave * 1024);
      }
    }
#pragma unroll
    for (int i = 0; i < BN / 32; ++i) {
      int off = i * 4096 + tid * 16;
      int row = off >> 7, b = off & 127;
      gload16((const char*)g.Bt + (size_t)(n0 + row) * 2048 + (k0 << 1) + b,
              lB + i * 4096 + wave * 1024);
    }
    __syncthreads();
#pragma unroll
    for (int kk = 0; kk < 2; ++kk) {
      bf16x8 af[MT], bfr[NT];
#pragma unroll
      for (int mt = 0; mt < MT; ++mt) {
        int row = wr * (BM / WR) + mt * 16 + lo;
        if (AF32) {
          int base = (row << 8) + ((kk << 7) + (hi << 5));
          int sw = (row & 7) << 4;
          f32x4 a0 = *(const f32x4*)(lA + ((base) ^ sw));
          f32x4 a1 = *(const f32x4*)(lA + ((base + 16) ^ sw));
          bf16x8 v;
#pragma unroll
          for (int j = 0; j < 4; ++j) { v[j] = (__bf16)a0[j]; v[4 + j] = (__bf16)a1[j]; }
          af[mt] = v;
        } else {
          int ob = (row << 7) + ((((kk << 2) + hi) << 4) ^ ((row & 7) << 4));
          af[mt] = *(const bf16x8*)(lA + ob);
        }
      }
#pragma unroll
      for (int nt = 0; nt < NT; ++nt) {
        int row = wc * (BN / WC) + nt * 16 + lo;
        int ob = (row << 7) + ((((kk << 2) + hi) << 4) ^ ((row & 7) << 4));
        bfr[nt] = *(const bf16x8*)(lB + ob);
      }
#pragma unroll
      for (int mt = 0; mt < MT; ++mt)
#pragma unroll
        for (int nt = 0; nt < NT; ++nt)
          acc[mt][nt] = mfma16(af[mt], bfr[nt], acc[mt][nt]);
    }
    __syncthreads();
  }

  // epilogue
#pragma unroll
  for (int mt = 0; mt < MT; ++mt) {
#pragma unroll
    for (int nt = 0; nt < NT; ++nt) {
      int col = n0 + wc * (BN / WC) + nt * 16 + lo;
      float bs = g.bias[col];
      int row0 = m0 + wr * (BM / WR) + mt * 16 + (hi << 2);
      float vj[4];
#pragma unroll
      for (int j = 0; j < 4; ++j) vj[j] = (acc[mt][nt][j] + bs) * g.scale;
      if (EPI == 1) {
#pragma unroll
        for (int j = 0; j < 4; ++j)
          ((float*)g.out)[(size_t)(row0 + j) * 1024 + col] = vj[j];
      } else if (blockIdx.z == 2) {
        // vt transposed (B,H,64,S) swizzled
        int d = col & 63;
        int bh = (row0 >> 11) * 16 + (col >> 6);
        int s = row0 & 2047;
        bf16x4 o;
#pragma unroll
        for (int j = 0; j < 4; ++j) o[j] = (__bf16)vj[j];
        char* p = (char*)g.out + ((size_t)bh << 18) + (size_t)d * 4096
                  + (s >> 6) * 128 + (((((s & 63) >> 3) ^ (d & 7)) << 4))
                  + ((s & 7) << 1);
        *(bf16x4*)p = o;
      } else {
        // head layout (B,H,S,64) swizzled
#pragma unroll
        for (int j = 0; j < 4; ++j) {
          int srow = row0 + j;
          size_t hb = ((size_t)((srow >> 11) * 16 + (col >> 6))) << 18;
          int ib = ((srow & 2047) << 7) + (((col & 63) << 1) ^ ((srow & 7) << 4));
          *(__bf16*)((char*)g.out + hb + ib) = (__bf16)vj[j];
        }
      }
    }
  }
}

// ---------------------------------------------------------------------------
// Fused attention. R9: 128-k-col rounds in BOTH passes (4x 8KB LDS tiles).
// Pass 1: dbuf over tile-pairs, vmcnt(2), 16 rounds. Pass 2: stage K0,K1,V0,V1
// then two halves back-to-back with no intermediate barrier (pf is wave-
// private); raw s_barrier at round end (no waitcnt drain needed there).
// ---------------------------------------------------------------------------
__global__ __launch_bounds__(512, 4) void attn_k(
    const unsigned short* __restrict__ qh, const unsigned short* __restrict__ kh,
    const unsigned short* __restrict__ vt, const int* __restrict__ mask,
    float* __restrict__ attn, unsigned short* __restrict__ ctx) {
  constexpr int S = 2048;
  __shared__ unsigned short buf[4][64 * 64];
  __shared__ unsigned long long mkb[32];
  __shared__ float pf[8][16 * 68];

  int tid = threadIdx.x, wave = tid >> 6, lane = tid & 63;
  int hi = lane >> 4, lo = lane & 15;
  int f = blockIdx.y * 16 + blockIdx.x;
  int xcd = f & 7, slot = f >> 3;          // 64 slots per XCD
  int bh = xcd * 4 + (slot & 3);
  int qb = slot >> 2;                      // 0..15, 128 q-rows each
  int b = bh >> 4, h = bh & 15;
  const char* khead = (const char*)kh + ((size_t)bh << 18);
  const char* qhead = (const char*)qh + ((size_t)bh << 18);
  const char* vhead = (const char*)vt + ((size_t)bh << 18);

  for (int it = 0; it < 4; ++it) {
    unsigned long long bal = __ballot(mask[b * S + it * 512 + tid] != 0);
    if (lane == 0) mkb[it * 8 + wave] = bal;
  }
  __syncthreads();

  int q0 = qb * 128 + wave * 16;
  bf16x8 qf[2];
  {
    int row = q0 + lo;
#pragma unroll
    for (int kk = 0; kk < 2; ++kk) {
      int ib = (row << 7) + ((((kk << 2) + hi) << 4) ^ ((row & 7) << 4));
      qf[kk] = *(const bf16x8*)(qhead + ib);
    }
  }

  float lsum[4] = {0.f, 0.f, 0.f, 0.f};

  // ---- pass 1: row sums, 128-col rounds, dbuf over tile-pairs ----
#pragma unroll
  for (int i = 0; i < 2; ++i)
    gload16(khead + (size_t)i * 8192 + tid * 16, (char*)buf[i] + wave * 1024);
  for (int t = 0; t < 16; ++t) {
    int p = (t & 1) << 1;   // current pair base: 0 or 2
    if (t < 15) {
#pragma unroll
      for (int i = 0; i < 2; ++i)
        gload16(khead + (size_t)(2 * t + 2 + i) * 8192 + tid * 16,
                (char*)buf[(p ^ 2) + i] + wave * 1024);
      asm volatile("s_waitcnt vmcnt(2)" ::: "memory");
    } else {
      asm volatile("s_waitcnt vmcnt(0)" ::: "memory");
    }
    __builtin_amdgcn_sched_barrier(0);
    __builtin_amdgcn_s_barrier();
    __builtin_amdgcn_s_setprio(1);
#pragma unroll
    for (int half = 0; half < 2; ++half) {
      unsigned long long mw = mkb[2 * t + half];
      const char* cb = (const char*)buf[p + half];
#pragma unroll
      for (int nt = 0; nt < 4; ++nt) {
        int r = nt * 16 + lo;
        f32x4 a = {0.f, 0.f, 0.f, 0.f};
#pragma unroll
        for (int kk = 0; kk < 2; ++kk) {
          int ob = (r << 7) + ((((kk << 2) + hi) << 4) ^ ((r & 7) << 4));
          a = mfma16(qf[kk], *(const bf16x8*)(cb + ob), a);
        }
        bool ok = (mw >> r) & 1ull;
#pragma unroll
        for (int j = 0; j < 4; ++j) lsum[j] += ok ? EXP2(a[j]) : 0.f;
      }
    }
    __builtin_amdgcn_s_setprio(0);
    __builtin_amdgcn_sched_barrier(0);
    __builtin_amdgcn_s_barrier();
    __builtin_amdgcn_sched_barrier(0);
  }

  float rcp[4];
#pragma unroll
  for (int j = 0; j < 4; ++j) {
    float s = lsum[j];
    s += __shfl_xor(s, 1); s += __shfl_xor(s, 2);
    s += __shfl_xor(s, 4); s += __shfl_xor(s, 8);
    rcp[j] = s > 0.f ? 1.0f / s : 0.f;
  }

  f32x4 cacc[4];
#pragma unroll
  for (int nt = 0; nt < 4; ++nt) cacc[nt] = (f32x4){0.f, 0.f, 0.f, 0.f};

  float* arow = attn + (size_t)bh * S * S;
  float* pfw = pf[wave];

  // ---- pass 2: 128-col rounds; K0,K1 in buf0/1, V0,V1 in buf2/3 ----
  for (int t = 0; t < 16; ++t) {
#pragma unroll
    for (int i = 0; i < 2; ++i)
      gload16(khead + (size_t)(2 * t + i) * 8192 + tid * 16,
              (char*)buf[i] + wave * 1024);
    {
      int d = tid >> 3, x = (tid & 7) * 16;
#pragma unroll
      for (int i = 0; i < 2; ++i)
        gload16(vhead + (size_t)d * 4096 + (2 * t + i) * 128 + x,
                (char*)buf[2 + i] + wave * 1024);
    }
    asm volatile("s_waitcnt vmcnt(0)" ::: "memory");
    __builtin_amdgcn_sched_barrier(0);
    __builtin_amdgcn_s_barrier();
    __builtin_amdgcn_sched_barrier(0);

#pragma unroll
    for (int half = 0; half < 2; ++half) {
      int kt = 2 * t + half;
      unsigned long long mw = mkb[kt];
      const char* kc = (const char*)buf[half];
      const char* vc = (const char*)buf[2 + half];
      __builtin_amdgcn_s_setprio(1);
#pragma unroll
      for (int nt = 0; nt < 4; ++nt) {
        int r = nt * 16 + lo;
        f32x4 a = {0.f, 0.f, 0.f, 0.f};
#pragma unroll
        for (int kk = 0; kk < 2; ++kk) {
          int ob = (r << 7) + ((((kk << 2) + hi) << 4) ^ ((r & 7) << 4));
          a = mfma16(qf[kk], *(const bf16x8*)(kc + ob), a);
        }
        bool ok = (mw >> r) & 1ull;
#pragma unroll
        for (int j = 0; j < 4; ++j) {
          float pn = ok ? EXP2(a[j]) * rcp[j] : 0.f;
          pfw[((hi << 2) + j) * 68 + r] = pn;
        }
      }
      __builtin_amdgcn_s_setprio(0);
      // attention store: 4 rows x 256B contiguous per dwordx4, nontemporal
      {
        int rsub = lane >> 4;
        int cb = (lane & 15) << 2;
#pragma unroll
        for (int s = 0; s < 4; ++s) {
          int row = s * 4 + rsub;
          f32x4 v = *(const f32x4*)&pfw[row * 68 + cb];
          __builtin_nontemporal_store(
              v, (f32x4*)(arow + (size_t)(q0 + row) * S + kt * 64 + cb));
        }
      }
      // PV from this half's V tile
      __builtin_amdgcn_s_setprio(1);
#pragma unroll
      for (int c = 0; c < 2; ++c) {
        f32x4 p0 = *(const f32x4*)&pfw[lo * 68 + c * 32 + hi * 8];
        f32x4 p1 = *(const f32x4*)&pfw[lo * 68 + c * 32 + hi * 8 + 4];
        bf16x8 pa;
#pragma unroll
        for (int i = 0; i < 4; ++i) { pa[i] = (__bf16)p0[i]; pa[4 + i] = (__bf16)p1[i]; }
#pragma unroll
        for (int nt = 0; nt < 4; ++nt) {
          int d = nt * 16 + lo;
          int ob = (d << 7) + ((((c << 2) + hi) << 4) ^ ((d & 7) << 4));
          cacc[nt] = mfma16(pa, *(const bf16x8*)(vc + ob), cacc[nt]);
        }
      }
      __builtin_amdgcn_s_setprio(0);
    }
    __builtin_amdgcn_sched_barrier(0);
    __builtin_amdgcn_s_barrier();
    __builtin_amdgcn_sched_barrier(0);
  }

  // context write, layout (B,S,1024) row-swizzled bf16 (already normalized)
#pragma unroll
  for (int nt = 0; nt < 4; ++nt) {
#pragma unroll
    for (int j = 0; j < 4; ++j) {
      int s = q0 + (hi << 2) + j;
      int mrow = b * S + s;
      int n = h * 64 + nt * 16 + lo;
      int ib = (n << 1) ^ ((mrow & 7) << 4);
      *(__bf16*)((char*)ctx + (size_t)mrow * 2048 + ib) = (__bf16)cacc[nt][j];
    }
  }
}

// ---------------------------------------------------------------------------
extern "C" void kernel_launch(void* const* d_in, const int* in_sizes, int n_in,
                              void* d_out, int out_size, void* d_ws, size_t ws_size,
                              hipStream_t stream) {
  const float* Q  = (const float*)d_in[0];
  const float* K  = (const float*)d_in[1];
  const float* V  = (const float*)d_in[2];
  const int* mask = (const int*)d_in[3];
  const float* WQ = (const float*)d_in[4];
  const float* bQ = (const float*)d_in[5];
  const float* WK = (const float*)d_in[6];
  const float* bK = (const float*)d_in[7];
  const float* WV = (const float*)d_in[8];
  const float* bV = (const float*)d_in[9];
  const float* WO = (const float*)d_in[10];
  const float* bO = (const float*)d_in[11];

  char* ws = (char*)d_ws;
  const size_t M1 = 1ull << 20;
  unsigned short* WQt = (unsigned short*)(ws + 0 * M1);
  unsigned short* WKt = (unsigned short*)(ws + 2 * M1);
  unsigned short* WVt = (unsigned short*)(ws + 4 * M1);
  unsigned short* WOt = (unsigned short*)(ws + 6 * M1);
  unsigned short* qh  = (unsigned short*)(ws + 8 * M1);
  unsigned short* kh  = (unsigned short*)(ws + 16 * M1);
  unsigned short* vt  = (unsigned short*)(ws + 24 * M1);
  unsigned short* ctx = (unsigned short*)(ws + 32 * M1);

  float* outF = (float*)d_out;                 // (B,S,1024) fp32
  float* attn = (float*)d_out + 4194304;       // (B,H,S,S) fp32

  const float qscale = 0.125f * 1.44269504088896340736f;

  transW4<<<dim3(16, 16, 4), dim3(256), 0, stream>>>(WQ, WK, WV, WO, WQt);

  GArg aq{Q, WQt, bQ, qh, qscale};
  GArg ak{K, WKt, bK, kh, 1.f};
  GArg av{V, WVt, bV, vt, 1.f};
  gemm_t<128, 128, 2, 2, 1, 0, 3><<<dim3(32, 8, 3), dim3(256), 0, stream>>>(aq, ak, av);

  attn_k<<<dim3(16, 32), dim3(512), 0, stream>>>(qh, kh, vt, mask, attn, ctx);

  GArg ao{ctx, WOt, bO, outF, 1.f};
  gemm_t<64, 128, 1, 4, 0, 1, 2><<<dim3(64, 8, 1), dim3(256), 0, stream>>>(ao, ao, ao);
}

// Round 10
// 233.240 us; speedup vs baseline: 1.0254x; 1.0254x over previous
//
#include <hip/hip_runtime.h>

typedef __attribute__((ext_vector_type(8))) __bf16 bf16x8;
typedef __attribute__((ext_vector_type(4))) __bf16 bf16x4;
typedef __attribute__((ext_vector_type(4))) float f32x4;

#define DEVFN static __device__ __forceinline__

#if __has_builtin(__builtin_amdgcn_exp2f)
#define EXP2(x) __builtin_amdgcn_exp2f(x)
#else
#define EXP2(x) exp2f(x)
#endif

DEVFN f32x4 mfma16(bf16x8 a, bf16x8 b, f32x4 c) {
  return __builtin_amdgcn_mfma_f32_16x16x32_bf16(a, b, c, 0, 0, 0);
}

DEVFN void gload16(const void* g, void* l) {
  __builtin_amdgcn_global_load_lds((const __attribute__((address_space(1))) void*)g,
                                   (__attribute__((address_space(3))) void*)l, 16, 0, 0);
}

// ---------------------------------------------------------------------------
// Transpose+convert weights: W fp32 [1024 k][1024 n] -> Wt bf16 [n][k] swizzled
// ---------------------------------------------------------------------------
__global__ __launch_bounds__(256) void transW4(const float* __restrict__ w0,
                                               const float* __restrict__ w1,
                                               const float* __restrict__ w2,
                                               const float* __restrict__ w3,
                                               unsigned short* __restrict__ obase) {
  __shared__ float t[64][65];
  const float* W = blockIdx.z == 0 ? w0 : blockIdx.z == 1 ? w1 : blockIdx.z == 2 ? w2 : w3;
  unsigned short* Wt = obase + ((size_t)blockIdx.z << 20);
  int k0 = blockIdx.x * 64, n0 = blockIdx.y * 64;
  int tid = threadIdx.x;
#pragma unroll
  for (int it = 0; it < 4; ++it) {
    int r = it * 16 + (tid >> 4);
    int c = (tid & 15) * 4;
    float4 v = *(const float4*)(W + (size_t)(k0 + r) * 1024 + n0 + c);
    t[r][c] = v.x; t[r][c + 1] = v.y; t[r][c + 2] = v.z; t[r][c + 3] = v.w;
  }
  __syncthreads();
#pragma unroll
  for (int it = 0; it < 2; ++it) {
    int nl = it * 32 + (tid >> 3);
    int kc = tid & 7;
    bf16x8 o;
#pragma unroll
    for (int j = 0; j < 8; ++j) o[j] = (__bf16)t[kc * 8 + j][nl];
    int n = n0 + nl;
    char* dst = (char*)Wt + (size_t)n * 2048 + (k0 << 1) + ((kc ^ (n & 7)) << 4);
    *(bf16x8*)dst = o;
  }
}

// ---------------------------------------------------------------------------
// GEMM C = A[4096x1024] * Bt[1024x1024]^T (+bias)*scale
// AF32=1: A raw fp32 row-major, reg-staged (load fp32 -> cvt -> swizzled
//         ds_write bf16). lA is bf16 (16KB) in all modes.
// ---------------------------------------------------------------------------
struct GArg {
  const void* A;
  const unsigned short* Bt;
  const float* bias;
  void* out;
  float scale;
};

template <int BM, int BN, int WR, int WC, int AF32, int EPI, int OCC>
__global__ __launch_bounds__(256, OCC) void gemm_t(GArg g0, GArg g1, GArg g2) {
  GArg g = blockIdx.z == 0 ? g0 : blockIdx.z == 1 ? g1 : g2;
  constexpr int MT = BM / WR / 16, NT = BN / WC / 16;
  __shared__ char lA[BM * 64 * 2];
  __shared__ char lB[BN * 64 * 2];
  int tid = threadIdx.x, wave = tid >> 6, lane = tid & 63;
  int hi = lane >> 4, lo = lane & 15;
  int m0 = blockIdx.x * BM, n0 = blockIdx.y * BN;
  int wr = wave / WC, wc = wave % WC;
  f32x4 acc[MT][NT];
#pragma unroll
  for (int mt = 0; mt < MT; ++mt)
#pragma unroll
    for (int nt = 0; nt < NT; ++nt) acc[mt][nt] = (f32x4){0.f, 0.f, 0.f, 0.f};

  for (int k0 = 0; k0 < 1024; k0 += 64) {
    if (AF32) {
      // reg-stage A: fp32 global -> cvt -> swizzled bf16 ds_write
#pragma unroll
      for (int it = 0; it < BM / 32; ++it) {
        int idx = it * 256 + tid;
        int row = idx >> 3;      // 0..BM-1
        int kc = idx & 7;        // 8-elem octet within the 64-k tile
        const float* src = (const float*)g.A + (size_t)(m0 + row) * 1024 + k0 + kc * 8;
        float4 a0 = *(const float4*)src;
        float4 a1 = *(const float4*)(src + 4);
        bf16x8 v;
#pragma unroll
        for (int j = 0; j < 4; ++j) { v[j] = (__bf16)(&a0.x)[j]; v[4 + j] = (__bf16)(&a1.x)[j]; }
        int ob = (row << 7) + ((kc << 4) ^ ((row & 7) << 4));
        *(bf16x8*)(lA + ob) = v;
      }
    } else {
#pragma unroll
      for (int i = 0; i < BM / 32; ++i) {
        int off = i * 4096 + tid * 16;
        int row = off >> 7, b = off & 127;
        gload16((const char*)g.A + (size_t)(m0 + row) * 2048 + (k0 << 1) + b,
                lA + i * 4096 + wave * 1024);
      }
    }
#pragma unroll
    for (int i = 0; i < BN / 32; ++i) {
      int off = i * 4096 + tid * 16;
      int row = off >> 7, b = off & 127;
      gload16((const char*)g.Bt + (size_t)(n0 + row) * 2048 + (k0 << 1) + b,
              lB + i * 4096 + wave * 1024);
    }
    __syncthreads();
#pragma unroll
    for (int kk = 0; kk < 2; ++kk) {
      bf16x8 af[MT], bfr[NT];
#pragma unroll
      for (int mt = 0; mt < MT; ++mt) {
        int row = wr * (BM / WR) + mt * 16 + lo;
        int ob = (row << 7) + ((((kk << 2) + hi) << 4) ^ ((row & 7) << 4));
        af[mt] = *(const bf16x8*)(lA + ob);
      }
#pragma unroll
      for (int nt = 0; nt < NT; ++nt) {
        int row = wc * (BN / WC) + nt * 16 + lo;
        int ob = (row << 7) + ((((kk << 2) + hi) << 4) ^ ((row & 7) << 4));
        bfr[nt] = *(const bf16x8*)(lB + ob);
      }
#pragma unroll
      for (int mt = 0; mt < MT; ++mt)
#pragma unroll
        for (int nt = 0; nt < NT; ++nt)
          acc[mt][nt] = mfma16(af[mt], bfr[nt], acc[mt][nt]);
    }
    __syncthreads();
  }

  // epilogue
#pragma unroll
  for (int mt = 0; mt < MT; ++mt) {
#pragma unroll
    for (int nt = 0; nt < NT; ++nt) {
      int col = n0 + wc * (BN / WC) + nt * 16 + lo;
      float bs = g.bias[col];
      int row0 = m0 + wr * (BM / WR) + mt * 16 + (hi << 2);
      float vj[4];
#pragma unroll
      for (int j = 0; j < 4; ++j) vj[j] = (acc[mt][nt][j] + bs) * g.scale;
      if (EPI == 1) {
#pragma unroll
        for (int j = 0; j < 4; ++j)
          ((float*)g.out)[(size_t)(row0 + j) * 1024 + col] = vj[j];
      } else if (blockIdx.z == 2) {
        // vt transposed (B,H,64,S) swizzled
        int d = col & 63;
        int bh = (row0 >> 11) * 16 + (col >> 6);
        int s = row0 & 2047;
        bf16x4 o;
#pragma unroll
        for (int j = 0; j < 4; ++j) o[j] = (__bf16)vj[j];
        char* p = (char*)g.out + ((size_t)bh << 18) + (size_t)d * 4096
                  + (s >> 6) * 128 + (((((s & 63) >> 3) ^ (d & 7)) << 4))
                  + ((s & 7) << 1);
        *(bf16x4*)p = o;
      } else {
        // head layout (B,H,S,64) swizzled
#pragma unroll
        for (int j = 0; j < 4; ++j) {
          int srow = row0 + j;
          size_t hb = ((size_t)((srow >> 11) * 16 + (col >> 6))) << 18;
          int ib = ((srow & 2047) << 7) + (((col & 63) << 1) ^ ((srow & 7) << 4));
          *(__bf16*)((char*)g.out + hb + ib) = (__bf16)vj[j];
        }
      }
    }
  }
}

// ---------------------------------------------------------------------------
// Fused attention — exact R8 structure (best-known: 512 threads, 8 waves,
// 128 q-rows/block, pass-1 dbuf vmcnt(1), pass-2 2-barrier, nt stores).
// ---------------------------------------------------------------------------
__global__ __launch_bounds__(512, 4) void attn_k(
    const unsigned short* __restrict__ qh, const unsigned short* __restrict__ kh,
    const unsigned short* __restrict__ vt, const int* __restrict__ mask,
    float* __restrict__ attn, unsigned short* __restrict__ ctx) {
  constexpr int S = 2048;
  __shared__ unsigned short ktl[64 * 64];
  __shared__ unsigned short vtl[64 * 64];
  __shared__ unsigned long long mkb[32];
  __shared__ float pf[8][16 * 68];

  int tid = threadIdx.x, wave = tid >> 6, lane = tid & 63;
  int hi = lane >> 4, lo = lane & 15;
  int f = blockIdx.y * 16 + blockIdx.x;
  int xcd = f & 7, slot = f >> 3;
  int bh = xcd * 4 + (slot & 3);
  int qb = slot >> 2;
  int b = bh >> 4, h = bh & 15;
  const char* khead = (const char*)kh + ((size_t)bh << 18);
  const char* qhead = (const char*)qh + ((size_t)bh << 18);
  const char* vhead = (const char*)vt + ((size_t)bh << 18);

  for (int it = 0; it < 4; ++it) {
    unsigned long long bal = __ballot(mask[b * S + it * 512 + tid] != 0);
    if (lane == 0) mkb[it * 8 + wave] = bal;
  }
  __syncthreads();

  int q0 = qb * 128 + wave * 16;
  bf16x8 qf[2];
  {
    int row = q0 + lo;
#pragma unroll
    for (int kk = 0; kk < 2; ++kk) {
      int ib = (row << 7) + ((((kk << 2) + hi) << 4) ^ ((row & 7) << 4));
      qf[kk] = *(const bf16x8*)(qhead + ib);
    }
  }

  float lsum[4] = {0.f, 0.f, 0.f, 0.f};

  // ---- pass 1: row sums, dbuf K staging (1 gload/thread/tile) ----
  gload16(khead + tid * 16, (char*)ktl + wave * 1024);
  for (int kt = 0; kt < 32; ++kt) {
    const char* cb = (kt & 1) ? (const char*)vtl : (const char*)ktl;
    char* nb = (kt & 1) ? (char*)ktl : (char*)vtl;
    if (kt < 31) {
      gload16(khead + (size_t)(kt + 1) * 8192 + tid * 16, nb + wave * 1024);
      asm volatile("s_waitcnt vmcnt(1)" ::: "memory");
    } else {
      asm volatile("s_waitcnt vmcnt(0)" ::: "memory");
    }
    __builtin_amdgcn_sched_barrier(0);
    __builtin_amdgcn_s_barrier();
    unsigned long long mw = mkb[kt];
    __builtin_amdgcn_s_setprio(1);
#pragma unroll
    for (int nt = 0; nt < 4; ++nt) {
      int r = nt * 16 + lo;
      f32x4 a = {0.f, 0.f, 0.f, 0.f};
#pragma unroll
      for (int kk = 0; kk < 2; ++kk) {
        int ob = (r << 7) + ((((kk << 2) + hi) << 4) ^ ((r & 7) << 4));
        a = mfma16(qf[kk], *(const bf16x8*)(cb + ob), a);
      }
      bool ok = (mw >> r) & 1ull;
#pragma unroll
      for (int j = 0; j < 4; ++j) lsum[j] += ok ? EXP2(a[j]) : 0.f;
    }
    __builtin_amdgcn_s_setprio(0);
    __builtin_amdgcn_sched_barrier(0);
    __builtin_amdgcn_s_barrier();
    __builtin_amdgcn_sched_barrier(0);
  }

  float rcp[4];
#pragma unroll
  for (int j = 0; j < 4; ++j) {
    float s = lsum[j];
    s += __shfl_xor(s, 1); s += __shfl_xor(s, 2);
    s += __shfl_xor(s, 4); s += __shfl_xor(s, 8);
    rcp[j] = s > 0.f ? 1.0f / s : 0.f;
  }

  f32x4 cacc[4];
#pragma unroll
  for (int nt = 0; nt < 4; ++nt) cacc[nt] = (f32x4){0.f, 0.f, 0.f, 0.f};

  float* arow = attn + (size_t)bh * S * S;
  float* pfw = pf[wave];

  // ---- pass 2: recompute, stage P in LDS, nt-store attn, PV ----
  for (int kt = 0; kt < 32; ++kt) {
    gload16(khead + (size_t)kt * 8192 + tid * 16, (char*)ktl + wave * 1024);
    {
      int d = tid >> 3, x = (tid & 7) * 16;
      gload16(vhead + (size_t)d * 4096 + kt * 128 + x, (char*)vtl + wave * 1024);
    }
    __syncthreads();
    unsigned long long mw = mkb[kt];
    __builtin_amdgcn_s_setprio(1);
#pragma unroll
    for (int nt = 0; nt < 4; ++nt) {
      int r = nt * 16 + lo;
      f32x4 a = {0.f, 0.f, 0.f, 0.f};
#pragma unroll
      for (int kk = 0; kk < 2; ++kk) {
        int ob = (r << 7) + ((((kk << 2) + hi) << 4) ^ ((r & 7) << 4));
        a = mfma16(qf[kk], *(const bf16x8*)((const char*)ktl + ob), a);
      }
      bool ok = (mw >> r) & 1ull;
#pragma unroll
      for (int j = 0; j < 4; ++j) {
        float pn = ok ? EXP2(a[j]) * rcp[j] : 0.f;
        pfw[((hi << 2) + j) * 68 + r] = pn;
      }
    }
    __builtin_amdgcn_s_setprio(0);
    // attention store: 4 rows x 256B contiguous per dwordx4, nontemporal
    {
      int rsub = lane >> 4;
      int cb = (lane & 15) << 2;
#pragma unroll
      for (int s = 0; s < 4; ++s) {
        int row = s * 4 + rsub;
        f32x4 v = *(const f32x4*)&pfw[row * 68 + cb];
        __builtin_nontemporal_store(
            v, (f32x4*)(arow + (size_t)(q0 + row) * S + kt * 64 + cb));
      }
    }
    // PV from current V buffer
    __builtin_amdgcn_s_setprio(1);
#pragma unroll
    for (int c = 0; c < 2; ++c) {
      f32x4 p0 = *(const f32x4*)&pfw[lo * 68 + c * 32 + hi * 8];
      f32x4 p1 = *(const f32x4*)&pfw[lo * 68 + c * 32 + hi * 8 + 4];
      bf16x8 pa;
#pragma unroll
      for (int i = 0; i < 4; ++i) { pa[i] = (__bf16)p0[i]; pa[4 + i] = (__bf16)p1[i]; }
#pragma unroll
      for (int nt = 0; nt < 4; ++nt) {
        int d = nt * 16 + lo;
        int ob = (d << 7) + ((((c << 2) + hi) << 4) ^ ((d & 7) << 4));
        cacc[nt] = mfma16(pa, *(const bf16x8*)((const char*)vtl + ob), cacc[nt]);
      }
    }
    __builtin_amdgcn_s_setprio(0);
    __syncthreads();
  }

  // context write, layout (B,S,1024) row-swizzled bf16 (already normalized)
#pragma unroll
  for (int nt = 0; nt < 4; ++nt) {
#pragma unroll
    for (int j = 0; j < 4; ++j) {
      int s = q0 + (hi << 2) + j;
      int mrow = b * S + s;
      int n = h * 64 + nt * 16 + lo;
      int ib = (n << 1) ^ ((mrow & 7) << 4);
      *(__bf16*)((char*)ctx + (size_t)mrow * 2048 + ib) = (__bf16)cacc[nt][j];
    }
  }
}

// ---------------------------------------------------------------------------
extern "C" void kernel_launch(void* const* d_in, const int* in_sizes, int n_in,
                              void* d_out, int out_size, void* d_ws, size_t ws_size,
                              hipStream_t stream) {
  const float* Q  = (const float*)d_in[0];
  const float* K  = (const float*)d_in[1];
  const float* V  = (const float*)d_in[2];
  const int* mask = (const int*)d_in[3];
  const float* WQ = (const float*)d_in[4];
  const float* bQ = (const float*)d_in[5];
  const float* WK = (const float*)d_in[6];
  const float* bK = (const float*)d_in[7];
  const float* WV = (const float*)d_in[8];
  const float* bV = (const float*)d_in[9];
  const float* WO = (const float*)d_in[10];
  const float* bO = (const float*)d_in[11];

  char* ws = (char*)d_ws;
  const size_t M1 = 1ull << 20;
  unsigned short* WQt = (unsigned short*)(ws + 0 * M1);
  unsigned short* WKt = (unsigned short*)(ws + 2 * M1);
  unsigned short* WVt = (unsigned short*)(ws + 4 * M1);
  unsigned short* WOt = (unsigned short*)(ws + 6 * M1);
  unsigned short* qh  = (unsigned short*)(ws + 8 * M1);
  unsigned short* kh  = (unsigned short*)(ws + 16 * M1);
  unsigned short* vt  = (unsigned short*)(ws + 24 * M1);
  unsigned short* ctx = (unsigned short*)(ws + 32 * M1);

  float* outF = (float*)d_out;                 // (B,S,1024) fp32
  float* attn = (float*)d_out + 4194304;       // (B,H,S,S) fp32

  const float qscale = 0.125f * 1.44269504088896340736f;

  transW4<<<dim3(16, 16, 4), dim3(256), 0, stream>>>(WQ, WK, WV, WO, WQt);

  GArg aq{Q, WQt, bQ, qh, qscale};
  GArg ak{K, WKt, bK, kh, 1.f};
  GArg av{V, WVt, bV, vt, 1.f};
  gemm_t<128, 128, 2, 2, 1, 0, 4><<<dim3(32, 8, 3), dim3(256), 0, stream>>>(aq, ak, av);

  attn_k<<<dim3(16, 32), dim3(512), 0, stream>>>(qh, kh, vt, mask, attn, ctx);

  GArg ao{ctx, WOt, bO, outF, 1.f};
  gemm_t<64, 128, 1, 4, 0, 1, 2><<<dim3(64, 8, 1), dim3(256), 0, stream>>>(ao, ao, ao);
}

// Round 12
// 222.062 us; speedup vs baseline: 1.0770x; 1.0503x over previous
//
#include <hip/hip_runtime.h>

typedef __attribute__((ext_vector_type(8))) __bf16 bf16x8;
typedef __attribute__((ext_vector_type(4))) __bf16 bf16x4;
typedef __attribute__((ext_vector_type(4))) float f32x4;

#define DEVFN static __device__ __forceinline__

#if __has_builtin(__builtin_amdgcn_exp2f)
#define EXP2(x) __builtin_amdgcn_exp2f(x)
#else
#define EXP2(x) exp2f(x)
#endif

DEVFN f32x4 mfma16(bf16x8 a, bf16x8 b, f32x4 c) {
  return __builtin_amdgcn_mfma_f32_16x16x32_bf16(a, b, c, 0, 0, 0);
}

DEVFN void gload16(const void* g, void* l) {
  __builtin_amdgcn_global_load_lds((const __attribute__((address_space(1))) void*)g,
                                   (__attribute__((address_space(3))) void*)l, 16, 0, 0);
}

// ---------------------------------------------------------------------------
// Transpose+convert weights: W fp32 [1024 k][1024 n] -> Wt bf16 [n][k] swizzled
// ---------------------------------------------------------------------------
__global__ __launch_bounds__(256) void transW4(const float* __restrict__ w0,
                                               const float* __restrict__ w1,
                                               const float* __restrict__ w2,
                                               const float* __restrict__ w3,
                                               unsigned short* __restrict__ obase) {
  __shared__ float t[64][65];
  const float* W = blockIdx.z == 0 ? w0 : blockIdx.z == 1 ? w1 : blockIdx.z == 2 ? w2 : w3;
  unsigned short* Wt = obase + ((size_t)blockIdx.z << 20);
  int k0 = blockIdx.x * 64, n0 = blockIdx.y * 64;
  int tid = threadIdx.x;
#pragma unroll
  for (int it = 0; it < 4; ++it) {
    int r = it * 16 + (tid >> 4);
    int c = (tid & 15) * 4;
    float4 v = *(const float4*)(W + (size_t)(k0 + r) * 1024 + n0 + c);
    t[r][c] = v.x; t[r][c + 1] = v.y; t[r][c + 2] = v.z; t[r][c + 3] = v.w;
  }
  __syncthreads();
#pragma unroll
  for (int it = 0; it < 2; ++it) {
    int nl = it * 32 + (tid >> 3);
    int kc = tid & 7;
    bf16x8 o;
#pragma unroll
    for (int j = 0; j < 8; ++j) o[j] = (__bf16)t[kc * 8 + j][nl];
    int n = n0 + nl;
    char* dst = (char*)Wt + (size_t)n * 2048 + (k0 << 1) + ((kc ^ (n & 7)) << 4);
    *(bf16x8*)dst = o;
  }
}

// ---------------------------------------------------------------------------
// GEMM C = A[4096x1024] * Bt[1024x1024]^T (+bias)*scale — exact R8 structure
// AF32=1: A raw fp32 via global_load_lds (32KB lA), cvt at fragment read.
// ---------------------------------------------------------------------------
struct GArg {
  const void* A;
  const unsigned short* Bt;
  const float* bias;
  void* out;
  float scale;
};

template <int BM, int BN, int WR, int WC, int AF32, int EPI, int OCC>
__global__ __launch_bounds__(256, OCC) void gemm_t(GArg g0, GArg g1, GArg g2) {
  GArg g = blockIdx.z == 0 ? g0 : blockIdx.z == 1 ? g1 : g2;
  constexpr int MT = BM / WR / 16, NT = BN / WC / 16;
  constexpr int AB = AF32 ? 4 : 2;
  __shared__ char lA[BM * 64 * AB];
  __shared__ char lB[BN * 64 * 2];
  int tid = threadIdx.x, wave = tid >> 6, lane = tid & 63;
  int hi = lane >> 4, lo = lane & 15;
  int m0 = blockIdx.x * BM, n0 = blockIdx.y * BN;
  int wr = wave / WC, wc = wave % WC;
  f32x4 acc[MT][NT];
#pragma unroll
  for (int mt = 0; mt < MT; ++mt)
#pragma unroll
    for (int nt = 0; nt < NT; ++nt) acc[mt][nt] = (f32x4){0.f, 0.f, 0.f, 0.f};

  for (int k0 = 0; k0 < 1024; k0 += 64) {
    if (AF32) {
#pragma unroll
      for (int i = 0; i < BM / 16; ++i) {
        int off = i * 4096 + tid * 16;
        int row = off >> 8, b = off & 255;
        gload16((const char*)g.A + (size_t)(m0 + row) * 4096 + (k0 << 2)
                    + (b ^ ((row & 7) << 4)),
                lA + i * 4096 + wave * 1024);
      }
    } else {
#pragma unroll
      for (int i = 0; i < BM / 32; ++i) {
        int off = i * 4096 + tid * 16;
        int row = off >> 7, b = off & 127;
        gload16((const char*)g.A + (size_t)(m0 + row) * 2048 + (k0 << 1) + b,
                lA + i * 4096 + wave * 1024);
      }
    }
#pragma unroll
    for (int i = 0; i < BN / 32; ++i) {
      int off = i * 4096 + tid * 16;
      int row = off >> 7, b = off & 127;
      gload16((const char*)g.Bt + (size_t)(n0 + row) * 2048 + (k0 << 1) + b,
              lB + i * 4096 + wave * 1024);
    }
    __syncthreads();
#pragma unroll
    for (int kk = 0; kk < 2; ++kk) {
      bf16x8 af[MT], bfr[NT];
#pragma unroll
      for (int mt = 0; mt < MT; ++mt) {
        int row = wr * (BM / WR) + mt * 16 + lo;
        if (AF32) {
          int base = (row << 8) + ((kk << 7) + (hi << 5));
          int sw = (row & 7) << 4;
          f32x4 a0 = *(const f32x4*)(lA + ((base) ^ sw));
          f32x4 a1 = *(const f32x4*)(lA + ((base + 16) ^ sw));
          bf16x8 v;
#pragma unroll
          for (int j = 0; j < 4; ++j) { v[j] = (__bf16)a0[j]; v[4 + j] = (__bf16)a1[j]; }
          af[mt] = v;
        } else {
          int ob = (row << 7) + ((((kk << 2) + hi) << 4) ^ ((row & 7) << 4));
          af[mt] = *(const bf16x8*)(lA + ob);
        }
      }
#pragma unroll
      for (int nt = 0; nt < NT; ++nt) {
        int row = wc * (BN / WC) + nt * 16 + lo;
        int ob = (row << 7) + ((((kk << 2) + hi) << 4) ^ ((row & 7) << 4));
        bfr[nt] = *(const bf16x8*)(lB + ob);
      }
#pragma unroll
      for (int mt = 0; mt < MT; ++mt)
#pragma unroll
        for (int nt = 0; nt < NT; ++nt)
          acc[mt][nt] = mfma16(af[mt], bfr[nt], acc[mt][nt]);
    }
    __syncthreads();
  }

  // epilogue
#pragma unroll
  for (int mt = 0; mt < MT; ++mt) {
#pragma unroll
    for (int nt = 0; nt < NT; ++nt) {
      int col = n0 + wc * (BN / WC) + nt * 16 + lo;
      float bs = g.bias[col];
      int row0 = m0 + wr * (BM / WR) + mt * 16 + (hi << 2);
      float vj[4];
#pragma unroll
      for (int j = 0; j < 4; ++j) vj[j] = (acc[mt][nt][j] + bs) * g.scale;
      if (EPI == 1) {
#pragma unroll
        for (int j = 0; j < 4; ++j)
          ((float*)g.out)[(size_t)(row0 + j) * 1024 + col] = vj[j];
      } else if (blockIdx.z == 2) {
        // vt transposed (B,H,64,S) swizzled
        int d = col & 63;
        int bh = (row0 >> 11) * 16 + (col >> 6);
        int s = row0 & 2047;
        bf16x4 o;
#pragma unroll
        for (int j = 0; j < 4; ++j) o[j] = (__bf16)vj[j];
        char* p = (char*)g.out + ((size_t)bh << 18) + (size_t)d * 4096
                  + (s >> 6) * 128 + (((((s & 63) >> 3) ^ (d & 7)) << 4))
                  + ((s & 7) << 1);
        *(bf16x4*)p = o;
      } else {
        // head layout (B,H,S,64) swizzled
#pragma unroll
        for (int j = 0; j < 4; ++j) {
          int srow = row0 + j;
          size_t hb = ((size_t)((srow >> 11) * 16 + (col >> 6))) << 18;
          int ib = ((srow & 2047) << 7) + (((col & 63) << 1) ^ ((srow & 7) << 4));
          *(__bf16*)((char*)g.out + hb + ib) = (__bf16)vj[j];
        }
      }
    }
  }
}

// ---------------------------------------------------------------------------
// Fused attention. R12 = R11 intent with the LDS size bug fixed:
// stg[4][64*64] (8KB per tile). Pass-1 pair-rounds (16 rounds, ping-pong
// pairs, vmcnt(2)); pass-2 byte-identical to R8. 512 thr / 8 waves /
// 128 q-rows per block; nt stores.
// ---------------------------------------------------------------------------
__global__ __launch_bounds__(512, 4) void attn_k(
    const unsigned short* __restrict__ qh, const unsigned short* __restrict__ kh,
    const unsigned short* __restrict__ vt, const int* __restrict__ mask,
    float* __restrict__ attn, unsigned short* __restrict__ ctx) {
  constexpr int S = 2048;
  __shared__ unsigned short stg[4][64 * 64];   // 4 x 8KB staging tiles
  __shared__ unsigned long long mkb[32];
  __shared__ float pf[8][16 * 68];

  int tid = threadIdx.x, wave = tid >> 6, lane = tid & 63;
  int hi = lane >> 4, lo = lane & 15;
  int f = blockIdx.y * 16 + blockIdx.x;
  int xcd = f & 7, slot = f >> 3;
  int bh = xcd * 4 + (slot & 3);
  int qb = slot >> 2;
  int b = bh >> 4, h = bh & 15;
  const char* khead = (const char*)kh + ((size_t)bh << 18);
  const char* qhead = (const char*)qh + ((size_t)bh << 18);
  const char* vhead = (const char*)vt + ((size_t)bh << 18);

  for (int it = 0; it < 4; ++it) {
    unsigned long long bal = __ballot(mask[b * S + it * 512 + tid] != 0);
    if (lane == 0) mkb[it * 8 + wave] = bal;
  }
  __syncthreads();

  int q0 = qb * 128 + wave * 16;
  bf16x8 qf[2];
  {
    int row = q0 + lo;
#pragma unroll
    for (int kk = 0; kk < 2; ++kk) {
      int ib = (row << 7) + ((((kk << 2) + hi) << 4) ^ ((row & 7) << 4));
      qf[kk] = *(const bf16x8*)(qhead + ib);
    }
  }

  float lsum[4] = {0.f, 0.f, 0.f, 0.f};

  // ---- pass 1: row sums, pair-rounds (2 K-tiles per barrier round) ----
#pragma unroll
  for (int i = 0; i < 2; ++i)
    gload16(khead + (size_t)i * 8192 + tid * 16, (char*)stg[i] + wave * 1024);
  for (int t = 0; t < 16; ++t) {
    int p = (t & 1) << 1;   // current pair base: 0 or 2
    if (t < 15) {
      int np = p ^ 2;
#pragma unroll
      for (int i = 0; i < 2; ++i)
        gload16(khead + (size_t)(2 * t + 2 + i) * 8192 + tid * 16,
                (char*)stg[np + i] + wave * 1024);
      asm volatile("s_waitcnt vmcnt(2)" ::: "memory");
    } else {
      asm volatile("s_waitcnt vmcnt(0)" ::: "memory");
    }
    __builtin_amdgcn_sched_barrier(0);
    __builtin_amdgcn_s_barrier();
    __builtin_amdgcn_s_setprio(1);
#pragma unroll
    for (int half = 0; half < 2; ++half) {
      unsigned long long mw = mkb[2 * t + half];
      const char* cb = (const char*)stg[p + half];
#pragma unroll
      for (int nt = 0; nt < 4; ++nt) {
        int r = nt * 16 + lo;
        f32x4 a = {0.f, 0.f, 0.f, 0.f};
#pragma unroll
        for (int kk = 0; kk < 2; ++kk) {
          int ob = (r << 7) + ((((kk << 2) + hi) << 4) ^ ((r & 7) << 4));
          a = mfma16(qf[kk], *(const bf16x8*)(cb + ob), a);
        }
        bool ok = (mw >> r) & 1ull;
#pragma unroll
        for (int j = 0; j < 4; ++j) lsum[j] += ok ? EXP2(a[j]) : 0.f;
      }
    }
    __builtin_amdgcn_s_setprio(0);
    __builtin_amdgcn_sched_barrier(0);
    __builtin_amdgcn_s_barrier();
    __builtin_amdgcn_sched_barrier(0);
  }

  float rcp[4];
#pragma unroll
  for (int j = 0; j < 4; ++j) {
    float s = lsum[j];
    s += __shfl_xor(s, 1); s += __shfl_xor(s, 2);
    s += __shfl_xor(s, 4); s += __shfl_xor(s, 8);
    rcp[j] = s > 0.f ? 1.0f / s : 0.f;
  }

  f32x4 cacc[4];
#pragma unroll
  for (int nt = 0; nt < 4; ++nt) cacc[nt] = (f32x4){0.f, 0.f, 0.f, 0.f};

  float* arow = attn + (size_t)bh * S * S;
  float* pfw = pf[wave];
  char* ktl = (char*)stg[0];
  char* vtl = (char*)stg[1];

  // ---- pass 2: exact R8 — recompute, stage P in LDS, nt-store attn, PV ----
  for (int kt = 0; kt < 32; ++kt) {
    gload16(khead + (size_t)kt * 8192 + tid * 16, ktl + wave * 1024);
    {
      int d = tid >> 3, x = (tid & 7) * 16;
      gload16(vhead + (size_t)d * 4096 + kt * 128 + x, vtl + wave * 1024);
    }
    __syncthreads();
    unsigned long long mw = mkb[kt];
    __builtin_amdgcn_s_setprio(1);
#pragma unroll
    for (int nt = 0; nt < 4; ++nt) {
      int r = nt * 16 + lo;
      f32x4 a = {0.f, 0.f, 0.f, 0.f};
#pragma unroll
      for (int kk = 0; kk < 2; ++kk) {
        int ob = (r << 7) + ((((kk << 2) + hi) << 4) ^ ((r & 7) << 4));
        a = mfma16(qf[kk], *(const bf16x8*)(ktl + ob), a);
      }
      bool ok = (mw >> r) & 1ull;
#pragma unroll
      for (int j = 0; j < 4; ++j) {
        float pn = ok ? EXP2(a[j]) * rcp[j] : 0.f;
        pfw[((hi << 2) + j) * 68 + r] = pn;
      }
    }
    __builtin_amdgcn_s_setprio(0);
    // attention store: 4 rows x 256B contiguous per dwordx4, nontemporal
    {
      int rsub = lane >> 4;
      int cb = (lane & 15) << 2;
#pragma unroll
      for (int s = 0; s < 4; ++s) {
        int row = s * 4 + rsub;
        f32x4 v = *(const f32x4*)&pfw[row * 68 + cb];
        __builtin_nontemporal_store(
            v, (f32x4*)(arow + (size_t)(q0 + row) * S + kt * 64 + cb));
      }
    }
    // PV from current V buffer
    __builtin_amdgcn_s_setprio(1);
#pragma unroll
    for (int c = 0; c < 2; ++c) {
      f32x4 p0 = *(const f32x4*)&pfw[lo * 68 + c * 32 + hi * 8];
      f32x4 p1 = *(const f32x4*)&pfw[lo * 68 + c * 32 + hi * 8 + 4];
      bf16x8 pa;
#pragma unroll
      for (int i = 0; i < 4; ++i) { pa[i] = (__bf16)p0[i]; pa[4 + i] = (__bf16)p1[i]; }
#pragma unroll
      for (int nt = 0; nt < 4; ++nt) {
        int d = nt * 16 + lo;
        int ob = (d << 7) + ((((c << 2) + hi) << 4) ^ ((d & 7) << 4));
        cacc[nt] = mfma16(pa, *(const bf16x8*)(vtl + ob), cacc[nt]);
      }
    }
    __builtin_amdgcn_s_setprio(0);
    __syncthreads();
  }

  // context write, layout (B,S,1024) row-swizzled bf16 (already normalized)
#pragma unroll
  for (int nt = 0; nt < 4; ++nt) {
#pragma unroll
    for (int j = 0; j < 4; ++j) {
      int s = q0 + (hi << 2) + j;
      int mrow = b * S + s;
      int n = h * 64 + nt * 16 + lo;
      int ib = (n << 1) ^ ((mrow & 7) << 4);
      *(__bf16*)((char*)ctx + (size_t)mrow * 2048 + ib) = (__bf16)cacc[nt][j];
    }
  }
}

// ---------------------------------------------------------------------------
extern "C" void kernel_launch(void* const* d_in, const int* in_sizes, int n_in,
                              void* d_out, int out_size, void* d_ws, size_t ws_size,
                              hipStream_t stream) {
  const float* Q  = (const float*)d_in[0];
  const float* K  = (const float*)d_in[1];
  const float* V  = (const float*)d_in[2];
  const int* mask = (const int*)d_in[3];
  const float* WQ = (const float*)d_in[4];
  const float* bQ = (const float*)d_in[5];
  const float* WK = (const float*)d_in[6];
  const float* bK = (const float*)d_in[7];
  const float* WV = (const float*)d_in[8];
  const float* bV = (const float*)d_in[9];
  const float* WO = (const float*)d_in[10];
  const float* bO = (const float*)d_in[11];

  char* ws = (char*)d_ws;
  const size_t M1 = 1ull << 20;
  unsigned short* WQt = (unsigned short*)(ws + 0 * M1);
  unsigned short* WKt = (unsigned short*)(ws + 2 * M1);
  unsigned short* WVt = (unsigned short*)(ws + 4 * M1);
  unsigned short* WOt = (unsigned short*)(ws + 6 * M1);
  unsigned short* qh  = (unsigned short*)(ws + 8 * M1);
  unsigned short* kh  = (unsigned short*)(ws + 16 * M1);
  unsigned short* vt  = (unsigned short*)(ws + 24 * M1);
  unsigned short* ctx = (unsigned short*)(ws + 32 * M1);

  float* outF = (float*)d_out;                 // (B,S,1024) fp32
  float* attn = (float*)d_out + 4194304;       // (B,H,S,S) fp32

  const float qscale = 0.125f * 1.44269504088896340736f;

  transW4<<<dim3(16, 16, 4), dim3(256), 0, stream>>>(WQ, WK, WV, WO, WQt);

  GArg aq{Q, WQt, bQ, qh, qscale};
  GArg ak{K, WKt, bK, kh, 1.f};
  GArg av{V, WVt, bV, vt, 1.f};
  gemm_t<128, 128, 2, 2, 1, 0, 3><<<dim3(32, 8, 3), dim3(256), 0, stream>>>(aq, ak, av);

  attn_k<<<dim3(16, 32), dim3(512), 0, stream>>>(qh, kh, vt, mask, attn, ctx);

  GArg ao{ctx, WOt, bO, outF, 1.f};
  gemm_t<64, 128, 1, 4, 0, 1, 2><<<dim3(64, 8, 1), dim3(256), 0, stream>>>(ao, ao, ao);
}